// Round 8
// baseline (1338.074 us; speedup 1.0000x reference)
//
#include <hip/hip_runtime.h>
#include <hip/hip_bf16.h>

typedef _Float16 f16x8 __attribute__((ext_vector_type(8)));
typedef _Float16 f16x4 __attribute__((ext_vector_type(4)));
typedef float f32x4 __attribute__((ext_vector_type(4)));
typedef float f32x16 __attribute__((ext_vector_type(16)));

#define MFMA16(A, B, C) __builtin_amdgcn_mfma_f32_16x16x32_f16((A), (B), (C), 0, 0, 0)
#define MFMA32(A, B, C) __builtin_amdgcn_mfma_f32_32x32x16_f16((A), (B), (C), 0, 0, 0)

#define DIMD 512
#define SEQ  8192
#define MTOT 16384  // 2*8192 rows

#define GLOAD16(gp, lp) __builtin_amdgcn_global_load_lds( \
    (const __attribute__((address_space(1))) void*)(gp),  \
    (__attribute__((address_space(3))) void*)(lp), 16, 0, 0)

#define LGKM0_BAR() do { \
    asm volatile("s_waitcnt lgkmcnt(0)" ::: "memory"); \
    __builtin_amdgcn_s_barrier(); \
    asm volatile("" ::: "memory"); } while (0)

// ---------------------------------------------------------------------------
// Projection GEMM: out[m][e] = sum_d x1[m][d] * W[e][d] + b[e], fp16 output.
// g==2 (V) is stored TRANSPOSED: Vt[b][e][s].
// ---------------------------------------------------------------------------
__global__ __launch_bounds__(256) void proj_kernel(
    const float* __restrict__ x1,
    const float* __restrict__ Wk, const float* __restrict__ bk,
    const float* __restrict__ Wq, const float* __restrict__ bq,
    const float* __restrict__ Wv, const float* __restrict__ bv,
    _Float16* __restrict__ Kh, _Float16* __restrict__ Qh, _Float16* __restrict__ Vt)
{
    const int g = blockIdx.z;
    const float* W    = (g == 0) ? Wk : (g == 1) ? Wq : Wv;
    const float* bias = (g == 0) ? bk : (g == 1) ? bq : bv;

    const int m0 = blockIdx.x * 128;
    const int n0 = blockIdx.y * 128;
    const int t  = threadIdx.x;
    const int lane = t & 63;
    const int w  = t >> 6;
    const int wr = w >> 1, wc = w & 1;
    const int lr = lane & 15;
    const int lkg = lane >> 4;
    const int lk = lkg * 8;

    __shared__ _Float16 Ah[128][40];
    __shared__ _Float16 Bh[128][40];

    f32x4 acc[4][4] = {};

    const int sr  = t >> 1;
    const int skh = (t & 1) * 16;

    for (int k0 = 0; k0 < DIMD; k0 += 32) {
        const float* sa = x1 + (size_t)(m0 + sr) * DIMD + k0 + skh;
        const float* sb = W  + (size_t)(n0 + sr) * DIMD + k0 + skh;
        _Float16 ta[16], tb[16];
        #pragma unroll
        for (int i = 0; i < 4; i++) {
            f32x4 va = *(const f32x4*)(sa + i * 4);
            f32x4 vb = *(const f32x4*)(sb + i * 4);
            #pragma unroll
            for (int u = 0; u < 4; u++) {
                ta[i * 4 + u] = (_Float16)va[u];
                tb[i * 4 + u] = (_Float16)vb[u];
            }
        }
        __syncthreads();
        *(f16x8*)&Ah[sr][skh]     = *(f16x8*)&ta[0];
        *(f16x8*)&Ah[sr][skh + 8] = *(f16x8*)&ta[8];
        *(f16x8*)&Bh[sr][skh]     = *(f16x8*)&tb[0];
        *(f16x8*)&Bh[sr][skh + 8] = *(f16x8*)&tb[8];
        __syncthreads();

        f16x8 af[4], bf[4];
        #pragma unroll
        for (int i = 0; i < 4; i++) af[i] = *(const f16x8*)&Ah[wr * 64 + i * 16 + lr][lk];
        #pragma unroll
        for (int j = 0; j < 4; j++) bf[j] = *(const f16x8*)&Bh[wc * 64 + j * 16 + lr][lk];
        #pragma unroll
        for (int i = 0; i < 4; i++)
            #pragma unroll
            for (int j = 0; j < 4; j++)
                acc[i][j] = MFMA16(af[i], bf[j], acc[i][j]);
    }

    const int col0 = n0 + wc * 64;
    const int row0 = m0 + wr * 64;
    #pragma unroll
    for (int j = 0; j < 4; j++) {
        float bval = bias[col0 + j * 16 + lr];
        #pragma unroll
        for (int i = 0; i < 4; i++) {
            #pragma unroll
            for (int jj = 0; jj < 4; jj++) {
                int mrow = row0 + i * 16 + lkg * 4 + jj;
                int e    = col0 + j * 16 + lr;
                float val = acc[i][j][jj] + bval;
                if (g == 2) {
                    Vt[(size_t)(mrow >> 13) * DIMD * SEQ + (size_t)e * SEQ + (mrow & 8191)] =
                        (_Float16)val;
                } else {
                    _Float16* outp = (g == 0) ? Kh : Qh;
                    outp[(size_t)mrow * DIMD + e] = (_Float16)val;
                }
            }
        }
    }
}

// ---------------------------------------------------------------------------
// Flash attention v8: v6 compute body + HARDWARE-TRUE XCD work assignment.
// Each physical XCD (read via s_getreg HW_REG_XCC_ID) owns one
// (batch, kv-quarter) combo: K 2MB + V 2MB = 4MB = its L2. Its 32 resident
// blocks claim 2 q-panels each via a per-XCD atomic slot counter (+ flags
// scan fallback for anomalous placement; any block can compute any panel,
// output identical -> deterministic). KV reads then hit the XCD's own L2
// regardless of inter-block drift.
// ctrl layout: [0..7] per-xcd slot counters, [8] scan counter,
//              [16..271] pair-claim flags.
// ---------------------------------------------------------------------------
__global__ __launch_bounds__(512, 2) void flash_dyn(
    const _Float16* __restrict__ Kh,   // role-Q rows
    const _Float16* __restrict__ Qh,   // role-K (softmax axis)
    const _Float16* __restrict__ Vt,   // role-V transposed [2][512][8192]
    _Float16* __restrict__ Opart,      // [4][MTOT][512]
    float* __restrict__ Ml,            // [4][MTOT][2]
    int* __restrict__ ctrl)
{
    const int t    = threadIdx.x;
    const int lane = t & 63;
    const int w    = t >> 6;          // 0..7
    const int q31  = lane & 31;
    const int h    = lane >> 5;       // 0/1
    const int mg   = w >> 1;          // m-group (32 rows each)
    const int kh   = w & 1;           // kv-half for QK^T

    __shared__ _Float16 Klds[64][512];   // role-K tile, row 16B-chunks XOR row&15
    __shared__ _Float16 Vlds[512][64];   // V^T tile, row 16B-chunks XOR row&7
    __shared__ _Float16 Plds[128][64];   // P, 8B slots XOR row&15
    __shared__ float Mbuf[8][32];
    __shared__ float Sbuf[8][32];
    __shared__ float Scl[128];
    __shared__ int NeedR;
    __shared__ int sh_pair;

    // ---- work claim: one pair of q-panels on THIS physical XCD's combo ----
    if (t == 0) {
        int xcc;
        asm volatile("s_getreg_b32 %0, hwreg(HW_REG_XCC_ID)" : "=s"(xcc));
        xcc &= 7;
        int s = __hip_atomic_fetch_add(&ctrl[xcc], 1, __ATOMIC_RELAXED,
                                       __HIP_MEMORY_SCOPE_AGENT);
        int pair = -1;
        if (s < 32) {
            int p = xcc * 32 + s;
            int old = __hip_atomic_exchange(&ctrl[16 + p], 1, __ATOMIC_RELAXED,
                                            __HIP_MEMORY_SCOPE_AGENT);
            if (old == 0) pair = p;
        }
        while (pair < 0) {   // anomalous placement: scavenge an unclaimed pair
            int g = __hip_atomic_fetch_add(&ctrl[8], 1, __ATOMIC_RELAXED,
                                           __HIP_MEMORY_SCOPE_AGENT) & 255;
            int old = __hip_atomic_exchange(&ctrl[16 + g], 1, __ATOMIC_RELAXED,
                                            __HIP_MEMORY_SCOPE_AGENT);
            if (old == 0) pair = g;
        }
        sh_pair = pair;
        NeedR = 0;
    }
    __syncthreads();
    const int pair    = sh_pair;
    const int combo   = pair >> 5;        // 0..7
    const int batch   = combo >> 2;       // 0..1
    const int quarter = combo & 3;        // 0..3
    const int qbase   = pair & 31;

    const _Float16* Qb = Qh + (size_t)batch * SEQ * DIMD;
    const _Float16* Vb = Vt + (size_t)batch * DIMD * SEQ;
    const int t0base = quarter * (SEQ / 4);
    const int NT = (SEQ / 4) / 64;        // 32 tiles per sweep

    // K stage: 8 rows/wave, pre-swizzled source (chunk L ^ (row&15))
    #define STAGE_K(it)                                                        \
    {                                                                          \
        const int t0s = t0base + (it) * 64;                                    \
        _Pragma("unroll")                                                      \
        for (int i = 0; i < 8; i++) {                                          \
            const int r = w * 8 + i;                                           \
            const char* src = (const char*)(Qb + (size_t)(t0s + r) * DIMD)     \
                              + ((lane ^ (r & 15)) << 4);                      \
            GLOAD16(src, (char*)&Klds[r][0]);                                  \
        }                                                                      \
    }
    // V stage: 64 d-rows/wave (8 gloads x 8 rows), source chunk (L&7)^(d&7)
    #define STAGE_V(it)                                                        \
    {                                                                          \
        const int t0v = t0base + (it) * 64;                                    \
        _Pragma("unroll")                                                      \
        for (int i = 0; i < 8; i++) {                                          \
            const int D0 = (w * 8 + i) * 8;                                    \
            const int dr = D0 + (lane >> 3);                                   \
            const _Float16* src = Vb + (size_t)dr * SEQ + t0v                  \
                                  + 8 * ((lane & 7) ^ (dr & 7));               \
            GLOAD16(src, (char*)&Vlds[D0][0]);                                 \
        }                                                                      \
    }

    STAGE_K(0);
    STAGE_V(0);

    for (int item = 0; item < 2; ++item) {
        const int qbl = qbase + 32 * item;
        const int R0  = batch * SEQ + qbl * 128;

        // role-Q fragments (nontemporal: don't pollute the KV-resident L2)
        const int qrow = R0 + mg * 32 + q31;
        f16x8 qf[32];
        #pragma unroll
        for (int ks = 0; ks < 32; ks++)
            qf[ks] = __builtin_nontemporal_load(
                (const f16x8*)(Kh + (size_t)qrow * DIMD + ks * 16 + h * 8));

        f32x16 Oacc[4][2] = {};
        float m_ = -1e30f, l_ = 0.f;

        for (int it = 0; it < NT; ++it) {
            const int itn = (it + 1 < NT) ? it + 1 : 0;  // wraps to next item's tile 0

            // TOP sync: K(t) and V(t) resident.
            asm volatile("s_waitcnt vmcnt(0)" ::: "memory");
            __builtin_amdgcn_s_barrier();
            asm volatile("" ::: "memory");

            // ---- QK^T: S^T[kv 32 (half kh)][q 32 (group mg)] ----
            f32x16 sT = {};
            const int krow = kh * 32 + q31;
            #pragma unroll
            for (int ks = 0; ks < 32; ks++) {
                const int ch = ((2 * ks + h) ^ (lane & 15)) << 4;
                f16x8 af = *(const f16x8*)((const char*)&Klds[krow][0] + ch);
                sT = MFMA32(af, qf[ks], sT);
            }

            // ---- softmax part 1: in-lane + half-swap max, publish wave max ----
            float mx = sT[0];
            #pragma unroll
            for (int r = 1; r < 16; r++) mx = fmaxf(mx, sT[r]);
            mx = fmaxf(mx, __shfl_xor(mx, 32, 64));
            if (lane < 32) Mbuf[w][lane] = mx;

            LGKM0_BAR();   // barrier A: Mbuf visible; all K reads done

            STAGE_K(itn);  // prefetch next K (safe: K reads complete)

            // ---- softmax part 2: defer-max, exp, partial sum, P pack+write ----
            float pm = fmaxf(mx, Mbuf[w ^ 1][q31]);
            float scale = 1.f;
            if (pm > m_ + 8.f) { scale = __expf(m_ - pm); m_ = pm; }
            float ps = 0.f;
            f16x4 pq[4];
            #pragma unroll
            for (int r = 0; r < 16; r++) {
                float p = __expf(sT[r] - m_);
                ps += p;
                pq[r >> 2][r & 3] = (_Float16)p;
            }
            ps += __shfl_xor(ps, 32, 64);
            if (lane < 32) {
                Sbuf[w][lane] = ps;
                if (kh == 0) Scl[mg * 32 + lane] = scale;
            }
            if (__any(scale != 1.f) && lane == 0) NeedR = 1;
            #pragma unroll
            for (int rq = 0; rq < 4; rq++) {
                int s  = kh * 8 + 2 * rq + h;
                int sp = s ^ (lane & 15);
                *(f16x4*)((char*)&Plds[mg * 32 + q31][0] + sp * 8) = pq[rq];
            }

            LGKM0_BAR();   // barrier B: P/Sbuf/Scl visible (V already resident)

            // ---- l update + conditional O rescale ----
            l_ = l_ * scale + (ps + Sbuf[w ^ 1][q31]);
            if (NeedR) {
                #pragma unroll
                for (int m2 = 0; m2 < 4; m2++) {
                    #pragma unroll
                    for (int rq = 0; rq < 4; rq++) {
                        f32x4 s4 = *(const f32x4*)&Scl[m2 * 32 + rq * 8 + 4 * h];
                        #pragma unroll
                        for (int n = 0; n < 2; n++)
                            #pragma unroll
                            for (int e = 0; e < 4; e++)
                                Oacc[m2][n][rq * 4 + e] *= s4[e];
                    }
                }
            }

            // ---- PV: O[128 q][64 d slice] += P[128x64] @ V[64 x 64-slice] ----
            #pragma unroll
            for (int ks = 0; ks < 4; ks++) {
                f16x8 vb[2];
                #pragma unroll
                for (int n = 0; n < 2; n++) {
                    const int dd = w * 64 + n * 32 + q31;
                    const int ch = ((2 * ks + h) ^ (dd & 7)) << 4;
                    vb[n] = *(const f16x8*)((const char*)&Vlds[dd][0] + ch);
                }
                #pragma unroll
                for (int m2 = 0; m2 < 4; m2++) {
                    const char* prow = (const char*)&Plds[m2 * 32 + q31][0];
                    const int s0 = ((4 * ks + 2 * h)     ^ (lane & 15)) * 8;
                    const int s1 = ((4 * ks + 2 * h + 1) ^ (lane & 15)) * 8;
                    f16x4 a0 = *(const f16x4*)(prow + s0);
                    f16x4 a1 = *(const f16x4*)(prow + s1);
                    f16x8 pa;
                    #pragma unroll
                    for (int e = 0; e < 4; e++) { pa[e] = a0[e]; pa[e + 4] = a1[e]; }
                    #pragma unroll
                    for (int n = 0; n < 2; n++)
                        Oacc[m2][n] = MFMA32(pa, vb[n], Oacc[m2][n]);
                }
            }

            LGKM0_BAR();   // barrier C: all V/P reads done
            if (t == 0) NeedR = 0;
            STAGE_V(itn);  // prefetch next V (drained at next tile top)
        }

        // ---- share 1/l + (m,l), normalize, nontemporal store ----
        if (kh == 0 && lane < 32) {
            Scl[mg * 32 + lane] = 1.f / l_;
            int R = R0 + mg * 32 + lane;
            __builtin_nontemporal_store(m_, &Ml[((size_t)quarter * MTOT + R) * 2]);
            __builtin_nontemporal_store(l_, &Ml[((size_t)quarter * MTOT + R) * 2 + 1]);
        }
        LGKM0_BAR();

        #pragma unroll
        for (int m2 = 0; m2 < 4; m2++) {
            #pragma unroll
            for (int rq = 0; rq < 4; rq++) {
                f32x4 li = *(const f32x4*)&Scl[m2 * 32 + rq * 8 + 4 * h];
                #pragma unroll
                for (int e = 0; e < 4; e++) {
                    int row = R0 + m2 * 32 + rq * 8 + 4 * h + e;
                    #pragma unroll
                    for (int n = 0; n < 2; n++) {
                        int d = w * 64 + n * 32 + q31;
                        float val = Oacc[m2][n][rq * 4 + e] * li[e];
                        __builtin_nontemporal_store(
                            (_Float16)val,
                            &Opart[((size_t)quarter * MTOT + row) * DIMD + d]);
                    }
                }
            }
        }
        LGKM0_BAR();   // Scl safe for next item
    }

    asm volatile("s_waitcnt vmcnt(0)" ::: "memory");  // drain dangling prefetch
    #undef STAGE_K
    #undef STAGE_V
}

// ---------------------------------------------------------------------------
// Combine 4 partials: out = sum_h a_h * O_h, a_h = e^{m_h-M} l_h / Z
// ---------------------------------------------------------------------------
__global__ __launch_bounds__(256) void combine_kernel(
    const _Float16* __restrict__ Opart, const float* __restrict__ Ml,
    float* __restrict__ out)
{
    size_t idx = (size_t)blockIdx.x * 256 + threadIdx.x;
    size_t e0 = idx * 8;
    int R = (int)(e0 >> 9);
    float m[4], l[4];
    float M = -1e30f;
    #pragma unroll
    for (int hh = 0; hh < 4; hh++) {
        m[hh] = Ml[((size_t)hh * MTOT + R) * 2];
        l[hh] = Ml[((size_t)hh * MTOT + R) * 2 + 1];
        M = fmaxf(M, m[hh]);
    }
    float a[4], Z = 0.f;
    #pragma unroll
    for (int hh = 0; hh < 4; hh++) { a[hh] = __expf(m[hh] - M) * l[hh]; Z += a[hh]; }
    float inv = 1.f / Z;
    float acc[8] = {};
    #pragma unroll
    for (int hh = 0; hh < 4; hh++) {
        f16x8 o = *(const f16x8*)(Opart + (size_t)hh * MTOT * DIMD + e0);
        float ah = a[hh] * inv;
        #pragma unroll
        for (int u = 0; u < 8; u++) acc[u] += ah * (float)o[u];
    }
    f32x4 r0, r1;
    #pragma unroll
    for (int u = 0; u < 4; u++) { r0[u] = acc[u]; r1[u] = acc[u + 4]; }
    *(f32x4*)(out + e0) = r0;
    *(f32x4*)(out + e0 + 4) = r1;
}

extern "C" void kernel_launch(void* const* d_in, const int* in_sizes, int n_in,
                              void* d_out, int out_size, void* d_ws, size_t ws_size,
                              hipStream_t stream) {
    (void)in_sizes; (void)n_in; (void)out_size;
    const float* x1 = (const float*)d_in[0];
    const float* Wk = (const float*)d_in[1];
    const float* bk = (const float*)d_in[2];
    const float* Wq = (const float*)d_in[3];
    const float* bq = (const float*)d_in[4];
    const float* Wv = (const float*)d_in[5];
    const float* bv = (const float*)d_in[6];
    float* out = (float*)d_out;

    _Float16* Kh = (_Float16*)d_ws;
    _Float16* Qh = Kh + (size_t)MTOT * DIMD;
    _Float16* Vt = Qh + (size_t)MTOT * DIMD;

    const size_t base = (size_t)MTOT * DIMD * 2 * 3;   // 48 MB
    const size_t opart_slice = (size_t)MTOT * DIMD * sizeof(_Float16);  // 16 MB
    _Float16* Opart = (_Float16*)((char*)d_ws + base);
    float*    Ml    = (float*)((char*)d_ws + base + 4 * opart_slice);
    int*      ctrl  = (int*)((char*)d_ws + base + 4 * opart_slice
                             + (size_t)4 * MTOT * 2 * sizeof(float));

    // mask output: 16 zero floats after the attention output
    hipMemsetAsync((char*)d_out + (size_t)MTOT * DIMD * sizeof(float), 0, 64, stream);
    // zero work-claim state (counters + flags) every launch (graph-safe)
    hipMemsetAsync(ctrl, 0, (16 + 256) * sizeof(int), stream);

    dim3 pg(128, 4, 3);
    proj_kernel<<<pg, 256, 0, stream>>>(x1, Wk, bk, Wq, bq, Wv, bv, Kh, Qh, Vt);

    flash_dyn<<<dim3(256), 512, 0, stream>>>(Kh, Qh, Vt, Opart, Ml, ctrl);
    combine_kernel<<<4096, 256, 0, stream>>>(Opart, Ml, out);
}

// Round 9
// 949.496 us; speedup vs baseline: 1.4092x; 1.4092x over previous
//
#include <hip/hip_runtime.h>
#include <hip/hip_bf16.h>

typedef _Float16 f16x8 __attribute__((ext_vector_type(8)));
typedef _Float16 f16x4 __attribute__((ext_vector_type(4)));
typedef float f32x4 __attribute__((ext_vector_type(4)));
typedef float f32x16 __attribute__((ext_vector_type(16)));

#define MFMA16(A, B, C) __builtin_amdgcn_mfma_f32_16x16x32_f16((A), (B), (C), 0, 0, 0)
#define MFMA32(A, B, C) __builtin_amdgcn_mfma_f32_32x32x16_f16((A), (B), (C), 0, 0, 0)

#define DIMD 512
#define SEQ  8192
#define MTOT 16384  // 2*8192 rows
#define TILE_F16 65536   // 128KB per kv-tile: K 64x512 (64KB) + V^T 512x64 (64KB)

#define GLOAD16(gp, lp) __builtin_amdgcn_global_load_lds( \
    (const __attribute__((address_space(1))) void*)(gp),  \
    (__attribute__((address_space(3))) void*)(lp), 16, 0, 0)

#define LGKM0_BAR() do { \
    asm volatile("s_waitcnt lgkmcnt(0)" ::: "memory"); \
    __builtin_amdgcn_s_barrier(); \
    asm volatile("" ::: "memory"); } while (0)

// ---------------------------------------------------------------------------
// Projection GEMM: out[m][e] = sum_d x1[m][d] * W[e][d] + b[e], fp16 output.
// g==0 (role-Q rows, from k-proj): linear row-major Kh[m][e].
// g==1 (role-K, from q-proj): packed pack[batch][tile][row 0..63][e] (64KB).
// g==2 (role-V, from v-proj): packed transposed pack[...][64KB + e*64 + s6].
// Packed layout makes flash staging a single contiguous 128KB stream per tile
// (DRAM row-buffer friendly) instead of 16KB-strided 128B reads.
// ---------------------------------------------------------------------------
__global__ __launch_bounds__(256) void proj_kernel(
    const float* __restrict__ x1,
    const float* __restrict__ Wk, const float* __restrict__ bk,
    const float* __restrict__ Wq, const float* __restrict__ bq,
    const float* __restrict__ Wv, const float* __restrict__ bv,
    _Float16* __restrict__ Kh, _Float16* __restrict__ pack)
{
    const int g = blockIdx.z;
    const float* W    = (g == 0) ? Wk : (g == 1) ? Wq : Wv;
    const float* bias = (g == 0) ? bk : (g == 1) ? bq : bv;

    const int m0 = blockIdx.x * 128;
    const int n0 = blockIdx.y * 128;
    const int t  = threadIdx.x;
    const int lane = t & 63;
    const int w  = t >> 6;
    const int wr = w >> 1, wc = w & 1;
    const int lr = lane & 15;
    const int lkg = lane >> 4;
    const int lk = lkg * 8;

    __shared__ _Float16 Ah[128][40];
    __shared__ _Float16 Bh[128][40];

    f32x4 acc[4][4] = {};

    const int sr  = t >> 1;
    const int skh = (t & 1) * 16;

    for (int k0 = 0; k0 < DIMD; k0 += 32) {
        const float* sa = x1 + (size_t)(m0 + sr) * DIMD + k0 + skh;
        const float* sb = W  + (size_t)(n0 + sr) * DIMD + k0 + skh;
        _Float16 ta[16], tb[16];
        #pragma unroll
        for (int i = 0; i < 4; i++) {
            f32x4 va = *(const f32x4*)(sa + i * 4);
            f32x4 vb = *(const f32x4*)(sb + i * 4);
            #pragma unroll
            for (int u = 0; u < 4; u++) {
                ta[i * 4 + u] = (_Float16)va[u];
                tb[i * 4 + u] = (_Float16)vb[u];
            }
        }
        __syncthreads();
        *(f16x8*)&Ah[sr][skh]     = *(f16x8*)&ta[0];
        *(f16x8*)&Ah[sr][skh + 8] = *(f16x8*)&ta[8];
        *(f16x8*)&Bh[sr][skh]     = *(f16x8*)&tb[0];
        *(f16x8*)&Bh[sr][skh + 8] = *(f16x8*)&tb[8];
        __syncthreads();

        f16x8 af[4], bf[4];
        #pragma unroll
        for (int i = 0; i < 4; i++) af[i] = *(const f16x8*)&Ah[wr * 64 + i * 16 + lr][lk];
        #pragma unroll
        for (int j = 0; j < 4; j++) bf[j] = *(const f16x8*)&Bh[wc * 64 + j * 16 + lr][lk];
        #pragma unroll
        for (int i = 0; i < 4; i++)
            #pragma unroll
            for (int j = 0; j < 4; j++)
                acc[i][j] = MFMA16(af[i], bf[j], acc[i][j]);
    }

    const int col0 = n0 + wc * 64;
    const int row0 = m0 + wr * 64;
    #pragma unroll
    for (int j = 0; j < 4; j++) {
        float bval = bias[col0 + j * 16 + lr];
        #pragma unroll
        for (int i = 0; i < 4; i++) {
            #pragma unroll
            for (int jj = 0; jj < 4; jj++) {
                int mrow = row0 + i * 16 + lkg * 4 + jj;
                int e    = col0 + j * 16 + lr;
                float val = acc[i][j][jj] + bval;
                _Float16 hv = (_Float16)val;
                const int batch = mrow >> 13;
                const int s     = mrow & 8191;
                if (g == 0) {
                    Kh[(size_t)mrow * DIMD + e] = hv;
                } else if (g == 1) {
                    // packed K region: tile = s>>6, row r = s&63
                    pack[((size_t)(batch * 128 + (s >> 6))) * TILE_F16
                         + (size_t)(s & 63) * DIMD + e] = hv;
                } else {
                    // packed V^T region: +32768 f16, row = e (64 f16 wide)
                    pack[((size_t)(batch * 128 + (s >> 6))) * TILE_F16
                         + 32768 + (size_t)e * 64 + (s & 63)] = hv;
                }
            }
        }
    }
}

// ---------------------------------------------------------------------------
// Flash attention v9: r5 compute body (KVBLK=64, 32x32x16 MFMA, in-lane
// softmax, defer-max) + TILE-PACKED staging: each tile's K and V^T live in
// one contiguous 128KB block -> staging is a sequential burst (DRAM
// row-locality), replacing the 16KB-strided V reads that capped effective
// BW at ~2.3 TB/s in r4-r8.
// ---------------------------------------------------------------------------
template<int SPLIT>
__global__ __launch_bounds__(512, 2) void flash_kernel(
    const _Float16* __restrict__ Kh,    // role-Q rows (linear)
    const _Float16* __restrict__ pack,  // packed K/V^T tiles
    float* __restrict__ out,            // SPLIT==1 path
    _Float16* __restrict__ Opart,       // [SPLIT][MTOT][512]
    float* __restrict__ Ml)             // [SPLIT][MTOT][2]
{
    const int B   = blockIdx.x;
    const int xcd = B & 7;
    int batch, s_idx, qbl;
    if constexpr (SPLIT == 2) {
        const int combo = xcd >> 1;
        batch = combo >> 1;
        s_idx = combo & 1;
        qbl   = (B >> 3) * 2 + (xcd & 1);   // grid 256
    } else {
        batch = xcd >> 2;
        s_idx = 0;
        qbl   = (B >> 3) * 4 + (xcd & 3);   // grid 128
    }
    const int R0 = batch * SEQ + qbl * 128;

    const int t    = threadIdx.x;
    const int lane = t & 63;
    const int w    = t >> 6;          // 0..7
    const int q31  = lane & 31;
    const int h    = lane >> 5;       // 0/1
    const int mg   = w >> 1;          // m-group (32 rows each)
    const int kh   = w & 1;           // kv-half for QK^T

    __shared__ _Float16 Klds[64][512];   // K tile, row 16B-chunks XOR row&15
    __shared__ _Float16 Vlds[512][64];   // V^T tile, 16B-chunks XOR d&7
    __shared__ _Float16 Plds[128][64];   // P, 8B slots XOR row&15
    __shared__ float Mbuf[8][32];
    __shared__ float Sbuf[8][32];
    __shared__ float Scl[128];
    __shared__ int NeedR;

    // role-Q fragments (nontemporal)
    const int qrow = R0 + mg * 32 + q31;
    f16x8 qf[32];
    #pragma unroll
    for (int ks = 0; ks < 32; ks++)
        qf[ks] = __builtin_nontemporal_load(
            (const f16x8*)(Kh + (size_t)qrow * DIMD + ks * 16 + h * 8));

    f32x16 Oacc[4][2] = {};
    float m_ = -1e30f, l_ = 0.f;

    const int t0base = s_idx * (SEQ / SPLIT);
    const int NT = (SEQ / SPLIT) / 64;
    const size_t packbase = (size_t)batch * 128;

    // K stage from packed tile: 8 rows/wave, pre-swizzled source chunks
    #define STAGE_K(it)                                                        \
    {                                                                          \
        const char* tb = (const char*)(pack +                                  \
            (packbase + (size_t)((t0base >> 6) + (it))) * TILE_F16);           \
        _Pragma("unroll")                                                      \
        for (int i = 0; i < 8; i++) {                                          \
            const int r = w * 8 + i;                                           \
            GLOAD16(tb + r * 1024 + ((lane ^ (r & 15)) << 4),                  \
                    (char*)&Klds[r][0]);                                       \
        }                                                                      \
    }
    // V stage from packed tile (V^T at +64KB): 64 d-rows/wave
    #define STAGE_V(it)                                                        \
    {                                                                          \
        const char* tb = (const char*)(pack +                                  \
            (packbase + (size_t)((t0base >> 6) + (it))) * TILE_F16) + 65536;   \
        _Pragma("unroll")                                                      \
        for (int i = 0; i < 8; i++) {                                          \
            const int D0 = (w * 8 + i) * 8;                                    \
            const int dr = D0 + (lane >> 3);                                   \
            GLOAD16(tb + dr * 128 + (((lane & 7) ^ (dr & 7)) << 4),            \
                    (char*)&Vlds[D0][0]);                                      \
        }                                                                      \
    }

    STAGE_K(0);
    STAGE_V(0);
    if (t == 0) NeedR = 0;

    for (int it = 0; it < NT; ++it) {
        // TOP sync: K(t) and V(t) resident.
        asm volatile("s_waitcnt vmcnt(0)" ::: "memory");
        __builtin_amdgcn_s_barrier();
        asm volatile("" ::: "memory");

        // ---- QK^T: S^T[kv 32 (half kh)][q 32 (group mg)] ----
        f32x16 sT = {};
        const int krow = kh * 32 + q31;
        #pragma unroll
        for (int ks = 0; ks < 32; ks++) {
            const int ch = ((2 * ks + h) ^ (lane & 15)) << 4;
            f16x8 af = *(const f16x8*)((const char*)&Klds[krow][0] + ch);
            sT = MFMA32(af, qf[ks], sT);
        }

        // ---- softmax part 1: in-lane + half-swap max, publish wave max ----
        float mx = sT[0];
        #pragma unroll
        for (int r = 1; r < 16; r++) mx = fmaxf(mx, sT[r]);
        mx = fmaxf(mx, __shfl_xor(mx, 32, 64));
        if (lane < 32) Mbuf[w][lane] = mx;

        LGKM0_BAR();   // barrier A: Mbuf visible; all K reads done

        if (it + 1 < NT) STAGE_K(it + 1);   // prefetch next K

        // ---- softmax part 2: defer-max, exp, partial sum, P pack+write ----
        float pm = fmaxf(mx, Mbuf[w ^ 1][q31]);
        float scale = 1.f;
        if (pm > m_ + 8.f) { scale = __expf(m_ - pm); m_ = pm; }
        float ps = 0.f;
        f16x4 pq[4];
        #pragma unroll
        for (int r = 0; r < 16; r++) {
            float p = __expf(sT[r] - m_);
            ps += p;
            pq[r >> 2][r & 3] = (_Float16)p;
        }
        ps += __shfl_xor(ps, 32, 64);
        if (lane < 32) {
            Sbuf[w][lane] = ps;
            if (kh == 0) Scl[mg * 32 + lane] = scale;
        }
        if (__any(scale != 1.f) && lane == 0) NeedR = 1;
        #pragma unroll
        for (int rq = 0; rq < 4; rq++) {
            int s  = kh * 8 + 2 * rq + h;
            int sp = s ^ (lane & 15);
            *(f16x4*)((char*)&Plds[mg * 32 + q31][0] + sp * 8) = pq[rq];
        }

        LGKM0_BAR();   // barrier B: P/Sbuf/Scl visible (V already resident)

        // ---- l update + conditional O rescale ----
        l_ = l_ * scale + (ps + Sbuf[w ^ 1][q31]);
        if (NeedR) {
            #pragma unroll
            for (int m2 = 0; m2 < 4; m2++) {
                #pragma unroll
                for (int rq = 0; rq < 4; rq++) {
                    f32x4 s4 = *(const f32x4*)&Scl[m2 * 32 + rq * 8 + 4 * h];
                    #pragma unroll
                    for (int n = 0; n < 2; n++)
                        #pragma unroll
                        for (int e = 0; e < 4; e++)
                            Oacc[m2][n][rq * 4 + e] *= s4[e];
                }
            }
        }

        // ---- PV: O[128 q][64 d slice] += P[128x64] @ V[64 x 64-slice] ----
        #pragma unroll
        for (int ks = 0; ks < 4; ks++) {
            f16x8 vb[2];
            #pragma unroll
            for (int n = 0; n < 2; n++) {
                const int dd = w * 64 + n * 32 + q31;
                const int ch = ((2 * ks + h) ^ (dd & 7)) << 4;
                vb[n] = *(const f16x8*)((const char*)&Vlds[dd][0] + ch);
            }
            #pragma unroll
            for (int m2 = 0; m2 < 4; m2++) {
                const char* prow = (const char*)&Plds[m2 * 32 + q31][0];
                const int s0 = ((4 * ks + 2 * h)     ^ (lane & 15)) * 8;
                const int s1 = ((4 * ks + 2 * h + 1) ^ (lane & 15)) * 8;
                f16x4 a0 = *(const f16x4*)(prow + s0);
                f16x4 a1 = *(const f16x4*)(prow + s1);
                f16x8 pa;
                #pragma unroll
                for (int e = 0; e < 4; e++) { pa[e] = a0[e]; pa[e + 4] = a1[e]; }
                #pragma unroll
                for (int n = 0; n < 2; n++)
                    Oacc[m2][n] = MFMA32(pa, vb[n], Oacc[m2][n]);
            }
        }

        LGKM0_BAR();   // barrier C: all V/P reads done
        if (t == 0) NeedR = 0;
        if (it + 1 < NT) STAGE_V(it + 1);   // prefetch next V
    }

    // ---- share 1/l (+ m,l for SPLIT), normalize, store (nontemporal) ----
    if (kh == 0 && lane < 32) {
        Scl[mg * 32 + lane] = 1.f / l_;
        if (SPLIT > 1) {
            int R = R0 + mg * 32 + lane;
            __builtin_nontemporal_store(m_, &Ml[((size_t)s_idx * MTOT + R) * 2]);
            __builtin_nontemporal_store(l_, &Ml[((size_t)s_idx * MTOT + R) * 2 + 1]);
        }
    }
    LGKM0_BAR();

    #pragma unroll
    for (int m2 = 0; m2 < 4; m2++) {
        #pragma unroll
        for (int rq = 0; rq < 4; rq++) {
            f32x4 li = *(const f32x4*)&Scl[m2 * 32 + rq * 8 + 4 * h];
            #pragma unroll
            for (int e = 0; e < 4; e++) {
                int row = R0 + m2 * 32 + rq * 8 + 4 * h + e;
                #pragma unroll
                for (int n = 0; n < 2; n++) {
                    int d = w * 64 + n * 32 + q31;
                    float val = Oacc[m2][n][rq * 4 + e] * li[e];
                    if (SPLIT == 1) {
                        out[(size_t)row * DIMD + d] = val;
                    } else {
                        __builtin_nontemporal_store(
                            (_Float16)val,
                            &Opart[((size_t)s_idx * MTOT + row) * DIMD + d]);
                    }
                }
            }
        }
    }
    #undef STAGE_K
    #undef STAGE_V
}

// ---------------------------------------------------------------------------
// Combine the SPLIT=2 halves: out = (a0*O0 + a1*O1), a_h = e^{m_h-M} l_h / Z
// ---------------------------------------------------------------------------
__global__ __launch_bounds__(256) void combine_kernel(
    const _Float16* __restrict__ Opart, const float* __restrict__ Ml,
    float* __restrict__ out)
{
    size_t idx = (size_t)blockIdx.x * 256 + threadIdx.x;
    size_t e0 = idx * 8;
    int R = (int)(e0 >> 9);
    float m0 = Ml[(size_t)R * 2],            l0 = Ml[(size_t)R * 2 + 1];
    float m1 = Ml[((size_t)MTOT + R) * 2],   l1 = Ml[((size_t)MTOT + R) * 2 + 1];
    float M  = fmaxf(m0, m1);
    float a0 = __expf(m0 - M) * l0;
    float a1 = __expf(m1 - M) * l1;
    float inv = 1.f / (a0 + a1);
    a0 *= inv; a1 *= inv;
    f16x8 o0 = __builtin_nontemporal_load((const f16x8*)(Opart + e0));
    f16x8 o1 = __builtin_nontemporal_load(
        (const f16x8*)(Opart + (size_t)MTOT * DIMD + e0));
    f32x4 r0, r1;
    #pragma unroll
    for (int u = 0; u < 4; u++) r0[u] = a0 * (float)o0[u] + a1 * (float)o1[u];
    #pragma unroll
    for (int u = 0; u < 4; u++) r1[u] = a0 * (float)o0[u + 4] + a1 * (float)o1[u + 4];
    *(f32x4*)(out + e0) = r0;
    *(f32x4*)(out + e0 + 4) = r1;
}

extern "C" void kernel_launch(void* const* d_in, const int* in_sizes, int n_in,
                              void* d_out, int out_size, void* d_ws, size_t ws_size,
                              hipStream_t stream) {
    (void)in_sizes; (void)n_in; (void)out_size;
    const float* x1 = (const float*)d_in[0];
    const float* Wk = (const float*)d_in[1];
    const float* bk = (const float*)d_in[2];
    const float* Wq = (const float*)d_in[3];
    const float* bq = (const float*)d_in[4];
    const float* Wv = (const float*)d_in[5];
    const float* bv = (const float*)d_in[6];
    float* out = (float*)d_out;

    _Float16* Kh   = (_Float16*)d_ws;                          // 16 MB
    _Float16* pack = Kh + (size_t)MTOT * DIMD;                 // 32 MB packed

    const size_t base = (size_t)MTOT * DIMD * 2 * 3;           // 48 MB total
    const size_t opart_slice = (size_t)MTOT * DIMD * sizeof(_Float16);  // 16 MB
    _Float16* Opart = (_Float16*)((char*)d_ws + base);

    // mask output: 16 zero floats after the attention output
    hipMemsetAsync((char*)d_out + (size_t)MTOT * DIMD * sizeof(float), 0, 64, stream);

    dim3 pg(128, 4, 3);
    proj_kernel<<<pg, 256, 0, stream>>>(x1, Wk, bk, Wq, bq, Wv, bv, Kh, pack);

    const size_t ml_bytes = (size_t)2 * MTOT * 2 * sizeof(float);
    const size_t need2 = base + 2 * opart_slice + ml_bytes;
    if (ws_size >= need2) {
        float* Ml = (float*)((char*)d_ws + base + 2 * opart_slice);
        flash_kernel<2><<<dim3(256), 512, 0, stream>>>(Kh, pack, out, Opart, Ml);
        combine_kernel<<<4096, 256, 0, stream>>>(Opart, Ml, out);
    } else {
        float* Ml = (float*)((char*)d_ws + base);  // unused by SPLIT=1
        flash_kernel<1><<<dim3(128), 512, 0, stream>>>(Kh, pack, out, Opart, Ml);
    }
}